// Round 19
// baseline (170.373 us; speedup 1.0000x reference)
//
#include <hip/hip_runtime.h>
#include <hip/hip_bf16.h>
#include <math.h>

#define HW 4096

typedef __attribute__((ext_vector_type(8))) short bf16x8;
typedef __attribute__((ext_vector_type(4))) float f32x4;

static __device__ __forceinline__ unsigned short f2bf(float x) {
    unsigned u = __float_as_uint(x);
    u += 0x7fffu + ((u >> 16) & 1u);     // RNE
    return (unsigned short)(u >> 16);
}
static __device__ __forceinline__ float bf2f(unsigned short h) {
    return __uint_as_float((unsigned)h << 16);
}
static __device__ __forceinline__ float g4(const float4& v, int k) {
    return k == 0 ? v.x : k == 1 ? v.y : k == 2 ? v.z : v.w;
}

// ---------------- transpose+bf16: z=0 group(192)->X0T (+per-block channel sums),
//                  z=1 BGc(64)->BGcT
__global__ __launch_bounds__(256) void k_transpose2(
    const float* __restrict__ group, const float* __restrict__ BGc, int bstride,
    unsigned short* __restrict__ X0T, unsigned short* __restrict__ BGcT,
    float* __restrict__ xpart)
{
    extern __shared__ float lds[];          // [C][65]
    const int b = blockIdx.y, p0 = blockIdx.x << 6, t = threadIdx.x;
    const int z = blockIdx.z;
    const int C = z ? 64 : 192;
    const float* xb = (z ? BGc : group) + (size_t)b * bstride;
    unsigned short* outT = z ? BGcT : X0T;
    for (int idx = t; idx < (C << 6); idx += 256) {
        int c = idx >> 6, p = idx & 63;
        lds[c * 65 + p] = xb[(size_t)c * HW + p0 + p];
    }
    __syncthreads();
    unsigned short* ob = outT + ((size_t)b * HW + p0) * C;
    for (int idx = t; idx < (C << 6); idx += 256) {
        int p = idx / C, c = idx - p * C;
        ob[idx] = f2bf(lds[c * 65 + p]);
    }
    if (z == 0) {
        const int w = t >> 6, lane = t & 63;
        float* xp = xpart + ((size_t)b * 64 + blockIdx.x) * 192;
        for (int c = w; c < 192; c += 4) {
            float v = lds[c * 65 + lane];
            #pragma unroll
            for (int o = 32; o > 0; o >>= 1) v += __shfl_down(v, o, 64);
            if (lane == 0) xp[c] = v;
        }
    }
}

// 4x4 register-tiled 64x64x64 f32 GEMM from padded LDS (A[64][68], B[64][68] as B[k][c])
static __device__ __forceinline__ void gemm64_tile(
    const float* A, const float* B, int t, float acc[4][4])
{
    const int tr = t >> 4, tc = t & 15;
    #pragma unroll
    for (int i = 0; i < 4; ++i)
        #pragma unroll
        for (int j = 0; j < 4; ++j) acc[i][j] = 0.f;
    for (int k4 = 0; k4 < 64; k4 += 4) {
        float4 a[4], bb[4];
        #pragma unroll
        for (int i = 0; i < 4; ++i) a[i]  = *(const float4*)&A[(4 * tr + i) * 68 + k4];
        #pragma unroll
        for (int kk = 0; kk < 4; ++kk) bb[kk] = *(const float4*)&B[(k4 + kk) * 68 + 4 * tc];
        #pragma unroll
        for (int i = 0; i < 4; ++i)
            #pragma unroll
            for (int kk = 0; kk < 4; ++kk)
                #pragma unroll
                for (int j = 0; j < 4; ++j)
                    acc[i][j] = fmaf(g4(a[i], kk), g4(bb[kk], j), acc[i][j]);
    }
}

// ---------------- prep: bid<4 = scales(b) (xpart reduce + CA MLPs); bid>=4 = chain(x).
__global__ __launch_bounds__(256) void k_prep(
    const float* __restrict__ xpart,
    const float* __restrict__ wg1, const float* __restrict__ bg1,
    const float* __restrict__ cag_w1, const float* __restrict__ cag_b1,
    const float* __restrict__ cag_w2, const float* __restrict__ cag_b2,
    const float* __restrict__ wc1, const float* __restrict__ bc1,
    const float* __restrict__ cac_w1, const float* __restrict__ cac_b1,
    const float* __restrict__ cac_w2, const float* __restrict__ cac_b2,
    const float* __restrict__ wg2, const float* __restrict__ bg2,
    const float* __restrict__ wg3, const float* __restrict__ bg3,
    const float* __restrict__ wc2, const float* __restrict__ bc2,
    const float* __restrict__ wf, const float* __restrict__ fb,
    const float* __restrict__ wgw, const float* __restrict__ gbv,
    const float* __restrict__ wh,
    float* __restrict__ W3L, float* __restrict__ Uf,
    float* __restrict__ bQ0L, float* __restrict__ bK0,
    float* __restrict__ sgG, float* __restrict__ scG,
    unsigned short* __restrict__ whb, unsigned short* __restrict__ wg1bT)
{
    const float LOG2E = 1.4426950408889634f;
    __shared__ float sA[64 * 68], sB[64 * 68], sC[64 * 68];
    __shared__ float xm[192], pg[192], pc[64], zz[16];
    const int bid = blockIdx.x, t = threadIdx.x;

    if (bid >= 4) {
        const int x = bid - 4;
        #pragma unroll
        for (int j = 0; j < 16; ++j) {
            int idx = t + j * 256, r = idx >> 6, c = idx & 63;
            sA[r * 68 + c] = wf[idx];
            sB[r * 68 + c] = wg3[idx];
        }
        __syncthreads();
        float acc[4][4];
        gemm64_tile(sA, sB, t, acc);                   // V = wf@wg3
        {
            const int tr = t >> 4, tc = t & 15;
            #pragma unroll
            for (int i = 0; i < 4; ++i)
                #pragma unroll
                for (int j = 0; j < 4; ++j)
                    sC[(4 * tr + i) * 68 + 4 * tc + j] = acc[i][j];
        }
        __syncthreads();
        if (x == 0 && t < 64) {                        // bQ0L
            float a = fb[t];
            #pragma unroll 16
            for (int m = 0; m < 64; ++m) {
                a = fmaf(sC[t * 68 + m], bg2[m], a);
                a = fmaf(sA[t * 68 + m], bg3[m], a);
            }
            bQ0L[t] = a * LOG2E;
        }
        __syncthreads();
        for (int idx = t; idx < 3072; idx += 256) {    // sA[c][m] = wg2[m][x*48+c]
            int c = idx >> 6, m = idx & 63;
            sA[c * 68 + m] = wg2[m * 192 + x * 48 + c];
        }
        __syncthreads();
        {
            const int tr = t >> 4, tc = t & 15;
            float a2[4][3];
            #pragma unroll
            for (int i = 0; i < 4; ++i)
                #pragma unroll
                for (int j = 0; j < 3; ++j) a2[i][j] = 0.f;
            for (int k4 = 0; k4 < 64; k4 += 4) {
                float4 a[4], bb[3];
                #pragma unroll
                for (int i = 0; i < 4; ++i) a[i] = *(const float4*)&sC[(4 * tr + i) * 68 + k4];
                #pragma unroll
                for (int j = 0; j < 3; ++j) bb[j] = *(const float4*)&sA[(3 * tc + j) * 68 + k4];
                #pragma unroll
                for (int i = 0; i < 4; ++i)
                    #pragma unroll
                    for (int j = 0; j < 3; ++j)
                        #pragma unroll
                        for (int kk = 0; kk < 4; ++kk)
                            a2[i][j] = fmaf(g4(a[i], kk), g4(bb[j], kk), a2[i][j]);
            }
            #pragma unroll
            for (int i = 0; i < 4; ++i)
                #pragma unroll
                for (int j = 0; j < 3; ++j)
                    W3L[(4 * tr + i) * 192 + x * 48 + 3 * tc + j] = a2[i][j] * LOG2E;
        }
        if (x == 1) {                                   // U = wg@wc2, bK0
            __syncthreads();
            #pragma unroll
            for (int j = 0; j < 16; ++j) {
                int idx = t + j * 256, r = idx >> 6, c = idx & 63;
                sA[r * 68 + c] = wgw[idx];
                sB[r * 68 + c] = wc2[idx];
            }
            __syncthreads();
            float au[4][4];
            gemm64_tile(sA, sB, t, au);
            {
                const int tr = t >> 4, tc = t & 15;
                #pragma unroll
                for (int i = 0; i < 4; ++i)
                    #pragma unroll
                    for (int j = 0; j < 4; ++j)
                        Uf[(4 * tr + i) * 64 + 4 * tc + j] = au[i][j];
            }
            if (t < 64) {
                float a = gbv[t];
                #pragma unroll 16
                for (int m = 0; m < 64; ++m) a = fmaf(sA[t * 68 + m], bc2[m], a);
                bK0[t] = a;
            }
        }
        // wg1^T -> bf16 (rows ci = [48x,48x+48), cols mid)
        for (int idx = t; idx < 9216; idx += 256) {
            int ci = x * 48 + idx / 192, mid = idx % 192;
            wg1bT[(size_t)ci * 192 + mid] = f2bf(wg1[mid * 192 + ci]);
        }
        return;
    }

    // ---- scales role: b = bid
    const int b = bid, w = t >> 6, lane = t & 63;
    if (t < 192) {
        float a = 0.f;
        #pragma unroll 16
        for (int pb = 0; pb < 64; ++pb)
            a += xpart[((size_t)b * 64 + pb) * 192 + t];
        xm[t] = a * (1.0f / HW);
    }
    __syncthreads();
    for (int r = w; r < 192; r += 4) {
        float part = 0.f;
        #pragma unroll
        for (int j = 0; j < 3; ++j)
            part = fmaf(wg1[r * 192 + lane + 64 * j], xm[lane + 64 * j], part);
        #pragma unroll
        for (int o = 32; o > 0; o >>= 1) part += __shfl_down(part, o, 64);
        if (lane == 0) pg[r] = part + bg1[r];
    }
    for (int r = w; r < 64; r += 4) {
        float part = wc1[r * 64 + lane] * xm[64 + lane];
        #pragma unroll
        for (int o = 32; o > 0; o >>= 1) part += __shfl_down(part, o, 64);
        if (lane == 0) pc[r] = part + bc1[r];
    }
    __syncthreads();
    if (t < 12) {
        float a = cag_b1[t];
        #pragma unroll 16
        for (int i = 0; i < 192; ++i) a = fmaf(cag_w1[t * 192 + i], pg[i], a);
        zz[t] = fmaxf(a, 0.f);
    }
    if (t >= 64 && t < 68) {
        int r = t - 64;
        float a = cac_b1[r];
        #pragma unroll 16
        for (int i = 0; i < 64; ++i) a = fmaf(cac_w1[r * 64 + i], pc[i], a);
        zz[12 + r] = fmaxf(a, 0.f);
    }
    __syncthreads();
    if (t < 192) {
        float a = cag_b2[t];
        #pragma unroll
        for (int j = 0; j < 12; ++j) a = fmaf(cag_w2[t * 12 + j], zz[j], a);
        sgG[b * 192 + t] = 1.f / (1.f + __expf(-a));
    } else {
        int c = t - 192;
        float a = cac_b2[c];
        #pragma unroll
        for (int j = 0; j < 4; ++j) a = fmaf(cac_w2[c * 4 + j], zz[12 + j], a);
        scG[b * 64 + c] = 1.f / (1.f + __expf(-a));
    }
    if (b == 0) {
        #pragma unroll
        for (int j = 0; j < 16; ++j) whb[t + j * 256] = f2bf(wh[t + j * 256]);
    }
}

// ---------------- per-batch finalize: bid<192 -> WQs scale; 192..195 -> WK GEMM + biasK
__global__ __launch_bounds__(256) void k_wscale(
    const float* __restrict__ W3L, const float* __restrict__ Uf,
    const float* __restrict__ sgG, const float* __restrict__ scG,
    const float* __restrict__ wc1, const float* __restrict__ bc1,
    const float* __restrict__ bK0,
    unsigned short* __restrict__ WQs, unsigned short* __restrict__ WKb,
    float* __restrict__ biasK)
{
    const int bid = blockIdx.x, t = threadIdx.x;
    if (bid < 192) {
        int i = bid * 256 + t;
        int b = i / 12288, rem = i - b * 12288;
        int c = rem % 192;
        WQs[i] = f2bf(W3L[rem] * sgG[b * 192 + c]);
        return;
    }
    __shared__ float Usc[64 * 68], sW[64 * 68], u2[64];
    const int b = bid - 192;
    #pragma unroll
    for (int j = 0; j < 16; ++j) {
        int idx = t + j * 256, r = idx >> 6, c = idx & 63;
        Usc[r * 68 + c] = Uf[idx] * scG[b * 64 + c];
        sW[r * 68 + c]  = wc1[idx];
    }
    if (t < 64) u2[t] = scG[b * 64 + t] * bc1[t];
    __syncthreads();
    float acc[4][4];
    gemm64_tile(Usc, sW, t, acc);
    const int tr = t >> 4, tc = t & 15;
    #pragma unroll
    for (int i = 0; i < 4; ++i)
        #pragma unroll
        for (int j = 0; j < 4; ++j)
            WKb[(size_t)b * 4096 + (4 * tr + i) * 64 + 4 * tc + j] = f2bf(acc[i][j]);
    if (t < 64) {
        float a = bK0[t];
        #pragma unroll 16
        for (int m = 0; m < 64; ++m) a = fmaf(Uf[t * 64 + m], u2[m], a);
        biasK[b * 64 + t] = a;
    }
}

// ---------------- WQfull[b] = WQs[b] @ wg1 (MFMA, K=192) + biasQF = WQs@bg1 + bQ0L
// grid (3 ci-tiles of 64, B); 4 waves x 16 co.
__global__ __launch_bounds__(256) void k_wqfull(
    const unsigned short* __restrict__ WQs, const unsigned short* __restrict__ wg1bT,
    const float* __restrict__ bQ0L, const float* __restrict__ bg1,
    unsigned short* __restrict__ WQF, float* __restrict__ biasQF)
{
    const int t = threadIdx.x;
    const int w = t >> 6, lane = t & 63;
    const int gid = lane >> 4, cid = lane & 15;
    const int xci = blockIdx.x, b = blockIdx.y;
    const int ci0 = xci << 6, co16 = w << 4;
    const unsigned short* A = WQs + (size_t)b * 12288 + (size_t)co16 * 192;
    const f32x4 fz = {0.f, 0.f, 0.f, 0.f};
    f32x4 acc[4] = {fz, fz, fz, fz};
    for (int kc = 0; kc < 192; kc += 32) {
        bf16x8 a = *(const bf16x8*)(A + (size_t)cid * 192 + kc + 8 * gid);
        #pragma unroll
        for (int n = 0; n < 4; ++n) {
            bf16x8 bb = *(const bf16x8*)(wg1bT + (size_t)(ci0 + 16 * n + cid) * 192 + kc + 8 * gid);
            acc[n] = __builtin_amdgcn_mfma_f32_16x16x32_bf16(a, bb, acc[n], 0, 0, 0);
        }
    }
    #pragma unroll
    for (int n = 0; n < 4; ++n)
        #pragma unroll
        for (int r = 0; r < 4; ++r)
            WQF[(size_t)b * 12288 + (size_t)(co16 + 4 * gid + r) * 192 + ci0 + 16 * n + cid] =
                f2bf(acc[n][r]);
    if (xci == 0 && t < 64) {
        float a = bQ0L[t];
        #pragma unroll 16
        for (int m = 0; m < 192; ++m)
            a = fmaf(bf2f(WQs[(size_t)b * 12288 + t * 192 + m]), bg1[m], a);
        biasQF[b * 64 + t] = a;
    }
}

// ---------------- merged MFMA projections: y=0 Fq (X0T,K=192), y=1 Gk (X0T@64,K=64), y=2 Hv
__global__ __launch_bounds__(256) void k_proj(
    const unsigned short* __restrict__ X0T, const unsigned short* __restrict__ BGcT,
    const unsigned short* __restrict__ WQF, const float* __restrict__ biasQF,
    const unsigned short* __restrict__ WKb, const float* __restrict__ biasK,
    const unsigned short* __restrict__ whb, const float* __restrict__ h_b,
    unsigned short* __restrict__ FqT, unsigned short* __restrict__ GkT,
    unsigned short* __restrict__ hvN)
{
    const int t = threadIdx.x;
    const int w = t >> 6, lane = t & 63;
    const int gid = lane >> 4, cid = lane & 15;
    const int which = blockIdx.y;
    const int b = blockIdx.z;
    const int p0 = blockIdx.x << 6;
    const int co16 = w << 4;
    int Cin, kOff, ldx;
    const unsigned short *XT, *W;
    const float* bp;
    if (which == 0)      { XT = X0T;  ldx = 192; kOff = 0;  Cin = 192; W = WQF + (size_t)b * 12288; bp = biasQF + b * 64; }
    else if (which == 1) { XT = X0T;  ldx = 192; kOff = 64; Cin = 64;  W = WKb + (size_t)b * 4096;  bp = biasK + b * 64; }
    else                 { XT = BGcT; ldx = 64;  kOff = 0;  Cin = 64;  W = whb;                      bp = h_b; }
    const unsigned short* xrow = XT + (size_t)b * HW * ldx + kOff;
    const unsigned short* wr = W + (size_t)co16 * Cin;
    f32x4 acc[4];
    #pragma unroll
    for (int n = 0; n < 4; ++n)
        #pragma unroll
        for (int r = 0; r < 4; ++r)
            acc[n][r] = bp[co16 + 4 * gid + r];
    for (int kc = 0; kc < Cin; kc += 32) {
        bf16x8 a = *(const bf16x8*)(wr + (size_t)cid * Cin + kc + 8 * gid);
        #pragma unroll
        for (int n = 0; n < 4; ++n) {
            bf16x8 bfr = *(const bf16x8*)(xrow + (size_t)(p0 + 16 * n + cid) * ldx + kc + 8 * gid);
            acc[n] = __builtin_amdgcn_mfma_f32_16x16x32_bf16(a, bfr, acc[n], 0, 0, 0);
        }
    }
    #pragma unroll
    for (int n = 0; n < 4; ++n)
        #pragma unroll
        for (int r = 0; r < 4; ++r) {
            float v = acc[n][r];
            int co = co16 + 4 * gid + r;
            int p  = p0 + 16 * n + cid;
            if (which == 0)      FqT[((size_t)b * HW + p) * 64 + co] = f2bf(v);
            else if (which == 1) GkT[((size_t)b * HW + p) * 64 + co] = f2bf(v);
            else                 hvN[((size_t)b * 64 + co) * HW + p] = f2bf(v);
        }
}

// ---------------- MFMA attention (proven round-8/15 config, exp2, in-reg Hv^2).
__global__ __launch_bounds__(512, 2) void k_attn(
    const unsigned short* __restrict__ FqT, const unsigned short* __restrict__ GkT,
    const unsigned short* __restrict__ HvN,
    float* __restrict__ mb, float* __restrict__ sbuf)
{
    __shared__ __align__(16) char smem[65536];
    const int t = threadIdx.x;
    const int bid = blockIdx.x;
    const int b = (bid & 7) >> 1;
    const int qbase = (((bid >> 3) << 1) | (bid & 1)) << 6;
    const int w = t >> 6, lane = t & 63;
    const int gid = lane >> 4, cid = lane & 15;
    const size_t CQ = (size_t)HW * 64;
    const unsigned short* fqt = FqT + (size_t)b * CQ;
    const unsigned short* gkt = GkT + (size_t)b * CQ;
    const unsigned short* hv  = HvN + (size_t)b * CQ;
    unsigned short* Pw = (unsigned short*)smem + w * 4096;

    bf16x8 fqa[4][2];
    #pragma unroll
    for (int qt = 0; qt < 4; ++qt) {
        const unsigned short* fr = fqt + (size_t)(qbase + 16 * qt + cid) * 64 + 8 * gid;
        fqa[qt][0] = *(const bf16x8*)fr;
        fqa[qt][1] = *(const bf16x8*)(fr + 32);
    }
    bf16x8 ones;
    #pragma unroll
    for (int j = 0; j < 8; ++j) ones[j] = (short)0x3F80;

    const f32x4 fz = {0.f, 0.f, 0.f, 0.f};
    f32x4 am[4][4], a2[4][4], lac[4];
    #pragma unroll
    for (int qt = 0; qt < 4; ++qt) {
        lac[qt] = fz;
        #pragma unroll
        for (int n = 0; n < 4; ++n) { am[qt][n] = fz; a2[qt][n] = fz; }
    }

    const int k00 = w << 9;
    for (int it = 0; it < 8; ++it) {
        const int k0 = k00 + (it << 6);
        #pragma unroll
        for (int n = 0; n < 4; ++n) {
            const unsigned short* gr = gkt + (size_t)(k0 + 16 * n + cid) * 64 + 8 * gid;
            bf16x8 b0 = *(const bf16x8*)gr;
            bf16x8 b1 = *(const bf16x8*)(gr + 32);
            const int k = 16 * n + cid;
            #pragma unroll
            for (int qt = 0; qt < 4; ++qt) {
                f32x4 s = __builtin_amdgcn_mfma_f32_16x16x32_bf16(fqa[qt][0], b0, fz, 0, 0, 0);
                s = __builtin_amdgcn_mfma_f32_16x16x32_bf16(fqa[qt][1], b1, s, 0, 0, 0);
                #pragma unroll
                for (int r = 0; r < 4; ++r) {
                    int q = 4 * gid + r;
                    Pw[qt * 1024 + q * 64 + (((k >> 3) ^ (q & 7)) << 3) + (k & 7)] =
                        f2bf(__builtin_amdgcn_exp2f(s[r]));
                }
            }
        }
        bf16x8 pa[4][2];
        #pragma unroll
        for (int qt = 0; qt < 4; ++qt)
            #pragma unroll
            for (int kh = 0; kh < 2; ++kh)
                pa[qt][kh] = *(const bf16x8*)(Pw + qt * 1024 + cid * 64 +
                                              (((4 * kh + gid) ^ (cid & 7)) << 3));
        #pragma unroll
        for (int qt = 0; qt < 4; ++qt) {
            lac[qt] = __builtin_amdgcn_mfma_f32_16x16x32_bf16(pa[qt][0], ones, lac[qt], 0, 0, 0);
            lac[qt] = __builtin_amdgcn_mfma_f32_16x16x32_bf16(pa[qt][1], ones, lac[qt], 0, 0, 0);
        }
        #pragma unroll
        for (int n = 0; n < 4; ++n) {
            const unsigned short* hr = hv + (size_t)(16 * n + cid) * HW + k0;
            #pragma unroll
            for (int kh = 0; kh < 2; ++kh) {
                bf16x8 hb = *(const bf16x8*)(hr + 32 * kh + 8 * gid);
                bf16x8 h2;
                #pragma unroll
                for (int j = 0; j < 8; ++j) {
                    float v = bf2f((unsigned short)hb[j]);
                    h2[j] = (short)f2bf(v * v);
                }
                #pragma unroll
                for (int qt = 0; qt < 4; ++qt) {
                    am[qt][n] = __builtin_amdgcn_mfma_f32_16x16x32_bf16(pa[qt][kh], hb, am[qt][n], 0, 0, 0);
                    a2[qt][n] = __builtin_amdgcn_mfma_f32_16x16x32_bf16(pa[qt][kh], h2, a2[qt][n], 0, 0, 0);
                }
            }
        }
    }

    __syncthreads();
    float* lb = (float*)smem;
    #pragma unroll
    for (int qt = 0; qt < 4; ++qt)
        *(f32x4*)(lb + ((size_t)(w * 4 + qt) * 64 + lane) * 4) = lac[qt];
    __syncthreads();
    float* Lm = (float*)(smem + 32768);
    if (t < 256) {
        int qt = t >> 6, ls = t & 63;
        f32x4 s = fz;
        #pragma unroll
        for (int ww = 0; ww < 8; ++ww)
            s += *(const f32x4*)(lb + ((size_t)(ww * 4 + qt) * 64 + ls) * 4);
        *(f32x4*)(Lm + ((size_t)qt * 64 + ls) * 4) = s;
    }
    __syncthreads();
    float* ab = (float*)smem;
    f32x4 meanv = fz;
    for (int qt = 0; qt < 4; ++qt) {
        #pragma unroll
        for (int n = 0; n < 4; ++n)
            *(f32x4*)(ab + ((size_t)(w * 4 + n) * 64 + lane) * 4) = am[qt][n];
        __syncthreads();
        if (t < 256) {
            int n = t >> 6, ls = t & 63;
            f32x4 s = fz;
            #pragma unroll
            for (int ww = 0; ww < 8; ++ww)
                s += *(const f32x4*)(ab + ((size_t)(ww * 4 + n) * 64 + ls) * 4);
            f32x4 lv = *(const f32x4*)(Lm + ((size_t)qt * 64 + ls) * 4);
            #pragma unroll
            for (int r = 0; r < 4; ++r) meanv[r] = s[r] / lv[r];
            int q0s = qbase + 16 * qt + 4 * (ls >> 4);
            int c   = 16 * n + (ls & 15);
            *(f32x4*)(mb + (size_t)b * CQ + (size_t)c * HW + q0s) = meanv;
        }
        __syncthreads();
        #pragma unroll
        for (int n = 0; n < 4; ++n)
            *(f32x4*)(ab + ((size_t)(w * 4 + n) * 64 + lane) * 4) = a2[qt][n];
        __syncthreads();
        if (t < 256) {
            int n = t >> 6, ls = t & 63;
            f32x4 s = fz;
            #pragma unroll
            for (int ww = 0; ww < 8; ++ww)
                s += *(const f32x4*)(ab + ((size_t)(ww * 4 + n) * 64 + ls) * 4);
            f32x4 lv = *(const f32x4*)(Lm + ((size_t)qt * 64 + ls) * 4);
            f32x4 sv;
            #pragma unroll
            for (int r = 0; r < 4; ++r) {
                float sec = s[r] / lv[r];
                sv[r] = sqrtf(fmaxf(sec - meanv[r] * meanv[r], 0.f));
            }
            int q0s = qbase + 16 * qt + 4 * (ls >> 4);
            int c   = 16 * n + (ls & 15);
            *(f32x4*)(sbuf + (size_t)b * CQ + (size_t)c * HW + q0s) = sv;
        }
        __syncthreads();
    }
}

// ---------------- fused: mvn stats + transfer + cbam channel pools
__global__ __launch_bounds__(256) void k_transfer_f(
    const float* __restrict__ mb, const float* __restrict__ sb,
    const float* __restrict__ FG, const float* __restrict__ BG, int bstride,
    float* __restrict__ xb, float* __restrict__ pavg, float* __restrict__ pmaxb)
{
    __shared__ float fgl[4096];
    __shared__ float r1[4], r2[4];
    const int bc = blockIdx.x, t = threadIdx.x;
    const int b = bc >> 6, c = bc & 63;
    const size_t row = (size_t)bc * HW;
    const float* fg = FG + (size_t)b * bstride + (size_t)(64 + c) * HW;
    const float* bg = BG + (size_t)b * bstride + (size_t)(64 + c) * HW;
    float s = 0.f, s2 = 0.f;
    #pragma unroll
    for (int j = 0; j < 16; ++j) {
        int i = t + j * 256;
        float v = fg[i];
        fgl[i] = v;
        s += v; s2 += v * v;
    }
    #pragma unroll
    for (int o = 32; o > 0; o >>= 1) { s += __shfl_down(s, o, 64); s2 += __shfl_down(s2, o, 64); }
    if ((t & 63) == 0) { r1[t >> 6] = s; r2[t >> 6] = s2; }
    __syncthreads();
    float m  = (r1[0] + r1[1] + r1[2] + r1[3]) * (1.0f / HW);
    float e2 = (r2[0] + r2[1] + r2[2] + r2[3]) * (1.0f / HW);
    float rs = rsqrtf(fmaxf(e2 - m * m, 0.f) + 1e-5f);
    float psum = 0.f, pmax = -1e30f;
    #pragma unroll
    for (int j = 0; j < 16; ++j) {
        int q = t + j * 256;
        float xv = sb[row + q] * (fgl[q] - m) * rs + mb[row + q] + bg[q];
        xb[row + q] = xv;
        psum += xv; pmax = fmaxf(pmax, xv);
    }
    __syncthreads();
    #pragma unroll
    for (int o = 32; o > 0; o >>= 1) {
        psum += __shfl_down(psum, o, 64);
        pmax = fmaxf(pmax, __shfl_down(pmax, o, 64));
    }
    if ((t & 63) == 0) { r1[t >> 6] = psum; r2[t >> 6] = pmax; }
    __syncthreads();
    if (t == 0) {
        pavg[bc]  = (r1[0] + r1[1] + r1[2] + r1[3]) * (1.0f / HW);
        pmaxb[bc] = fmaxf(fmaxf(r2[0], r2[1]), fmaxf(r2[2], r2[3]));
    }
}

// ---------------- CBAM channel-scale (recomputed per block)
static __device__ __forceinline__ void cbam_scale(
    const float* __restrict__ pav, const float* __restrict__ pmx,
    const float* __restrict__ w1, const float* __restrict__ b1,
    const float* __restrict__ w2, const float* __restrict__ b2,
    int b, int t, float* scb)
{
    __shared__ float za[4], zm[4];
    if (t < 4) {
        float aa = b1[t], am = b1[t];
        #pragma unroll 16
        for (int i = 0; i < 64; ++i) {
            aa = fmaf(w1[t * 64 + i], pav[b * 64 + i], aa);
            am = fmaf(w1[t * 64 + i], pmx[b * 64 + i], am);
        }
        za[t] = fmaxf(aa, 0.f);
        zm[t] = fmaxf(am, 0.f);
    }
    __syncthreads();
    if (t < 64) {
        float a = 2.f * b2[t];
        #pragma unroll
        for (int j = 0; j < 4; ++j) a = fmaf(w2[t * 4 + j], za[j] + zm[j], a);
        scb[t] = 1.f / (1.f + __expf(-a));
    }
    __syncthreads();
}

// ---------------- spatial pool of (xb*s) with inlined cbam MLP
__global__ __launch_bounds__(256) void k_sp_pool(
    const float* __restrict__ xb,
    const float* __restrict__ pav, const float* __restrict__ pmx,
    const float* __restrict__ w1, const float* __restrict__ b1,
    const float* __restrict__ w2, const float* __restrict__ b2,
    float* __restrict__ spm, float* __restrict__ spx)
{
    __shared__ float scb[64];
    const int b = blockIdx.y, t = threadIdx.x;
    cbam_scale(pav, pmx, w1, b1, w2, b2, b, t, scb);
    const int p = blockIdx.x * 256 + t;
    const float* xp = xb + (size_t)b * 262144 + p;
    float sum = 0.f, mx = -1e30f;
    #pragma unroll 8
    for (int c = 0; c < 64; ++c) {
        float v = xp[(size_t)c * HW] * scb[c];
        sum += v;
        mx = fmaxf(mx, v);
    }
    spm[b * HW + p] = sum * (1.0f / 64.0f);
    spx[b * HW + p] = mx;
}

// ---------------- fused 7x7 spatial conv + sigmoid + final output
__global__ __launch_bounds__(256) void k_spf(
    const float* __restrict__ spm, const float* __restrict__ spx,
    const float* __restrict__ w, const float* __restrict__ bias,
    const float* __restrict__ xb,
    const float* __restrict__ pav, const float* __restrict__ pmx,
    const float* __restrict__ w1, const float* __restrict__ b1,
    const float* __restrict__ w2, const float* __restrict__ b2,
    float* __restrict__ out)
{
    __shared__ float scb[64];
    const int b = blockIdx.y, t = threadIdx.x;
    cbam_scale(pav, pmx, w1, b1, w2, b2, b, t, scb);
    const int p = blockIdx.x * 256 + t;
    const int y = p >> 6, x = p & 63;
    float acc = bias[0];
    for (int dy = 0; dy < 7; ++dy) {
        int yy = y + dy - 3;
        if (yy < 0 || yy >= 64) continue;
        for (int dx = 0; dx < 7; ++dx) {
            int xx = x + dx - 3;
            if (xx < 0 || xx >= 64) continue;
            int q = b * HW + yy * 64 + xx;
            acc = fmaf(spm[q], w[dy * 7 + dx],      acc);
            acc = fmaf(spx[q], w[49 + dy * 7 + dx], acc);
        }
    }
    float sgm = 1.f / (1.f + __expf(-acc));
    const float* xp = xb + (size_t)b * 262144 + p;
    float* op = out + (size_t)b * 262144 + p;
    #pragma unroll 8
    for (int c = 0; c < 64; ++c)
        op[(size_t)c * HW] = xp[(size_t)c * HW] * scb[c] * sgm;
}

extern "C" void kernel_launch(void* const* d_in, const int* in_sizes, int n_in,
                              void* d_out, int out_size, void* d_ws, size_t ws_size,
                              hipStream_t stream)
{
    const float* group  = (const float*)d_in[0];
    const float* FG     = (const float*)d_in[1];
    const float* BG     = (const float*)d_in[2];
    const float* wg1    = (const float*)d_in[3];
    const float* bg1    = (const float*)d_in[4];
    const float* cag_w1 = (const float*)d_in[5];
    const float* cag_b1 = (const float*)d_in[6];
    const float* cag_w2 = (const float*)d_in[7];
    const float* cag_b2 = (const float*)d_in[8];
    const float* wg2    = (const float*)d_in[9];
    const float* bg2    = (const float*)d_in[10];
    const float* wg3    = (const float*)d_in[11];
    const float* bg3    = (const float*)d_in[12];
    const float* wc1    = (const float*)d_in[13];
    const float* bc1    = (const float*)d_in[14];
    const float* cac_w1 = (const float*)d_in[15];
    const float* cac_b1 = (const float*)d_in[16];
    const float* cac_w2 = (const float*)d_in[17];
    const float* cac_b2 = (const float*)d_in[18];
    const float* wc2    = (const float*)d_in[19];
    const float* bc2    = (const float*)d_in[20];
    const float* f_w    = (const float*)d_in[21];
    const float* f_b    = (const float*)d_in[22];
    const float* g_w    = (const float*)d_in[23];
    const float* g_b    = (const float*)d_in[24];
    const float* h_w    = (const float*)d_in[25];
    const float* h_b    = (const float*)d_in[26];
    const float* mlp_w1 = (const float*)d_in[27];
    const float* mlp_b1 = (const float*)d_in[28];
    const float* mlp_w2 = (const float*)d_in[29];
    const float* mlp_b2 = (const float*)d_in[30];
    const float* sp_w   = (const float*)d_in[31];
    const float* sp_b   = (const float*)d_in[32];
    float* out = (float*)d_out;

    const int B = 4;
    const size_t CHW = (size_t)64 * HW;
    const int BST = (int)(3 * CHW);

    float* ws = (float*)d_ws;
    const size_t M = 1048576;
    unsigned short* X0T  = (unsigned short*)ws;                 // [0,1.5M)f
    unsigned short* BGcT = (unsigned short*)(ws + 3 * M / 2);   // [1.5M,2M)
    unsigned short* FqT  = (unsigned short*)(ws + 7 * M / 2);   // [3.5M,4M)
    unsigned short* GkT  = (unsigned short*)(ws + 4 * M);       // [4M,4.5M)
    unsigned short* hvN  = (unsigned short*)(ws + 9 * M / 2);   // [4.5M,5M)
    float* mbuf = ws + 5 * M;       // [5M,6M)
    float* sbuf = ws + 6 * M;       // [6M,7M)
    float* xb   = ws;               // [0,1M) over X0T (dead after proj)
    float* smalls = ws + 7 * M;
    float* xpart = smalls;             // 49152 = [4][64][192]
    float* sgG   = smalls + 49152;     // 768
    float* scG   = smalls + 49920;     // 256
    float* pav   = smalls + 50176;     // 256
    float* pmx   = smalls + 50432;     // 256
    float* biasK = smalls + 50688;     // 256
    float* bQ0L  = smalls + 50944;     // 64
    float* bK0   = smalls + 51008;     // 64
    float* biasQF= smalls + 51072;     // 256
    float* Uf    = smalls + 51328;     // 4096
    float* W3L   = smalls + 55424;     // 12288
    float* spm   = smalls + 67712;     // 16384
    float* spx   = smalls + 84096;     // 16384
    unsigned short* wsh = (unsigned short*)(smalls + 100480);
    unsigned short* WQs   = wsh;              // 49152
    unsigned short* WKb   = wsh + 49152;      // 16384
    unsigned short* whb   = wsh + 65536;      // 4096
    unsigned short* wg1bT = wsh + 69632;      // 36864
    unsigned short* WQF   = wsh + 106496;     // 49152

    dim3 blk(256);

    // 1. input transposes + per-block channel sums (no atomics)
    k_transpose2<<<dim3(64, B, 2), blk, 192 * 65 * 4, stream>>>(group, BG + CHW, BST, X0T, BGcT, xpart);
    // 2. scales (xpart reduce + CA MLPs) + weight chain (V, W3L, U, biases, wg1^T, whb)
    k_prep<<<8, blk, 0, stream>>>(
        xpart, wg1, bg1, cag_w1, cag_b1, cag_w2, cag_b2,
        wc1, bc1, cac_w1, cac_b1, cac_w2, cac_b2,
        wg2, bg2, wg3, bg3, wc2, bc2,
        f_w, f_b, g_w, g_b, h_w,
        W3L, Uf, bQ0L, bK0, sgG, scG, whb, wg1bT);
    // 3. per-batch WQ scale + WK GEMM + biasK
    k_wscale<<<196, blk, 0, stream>>>(W3L, Uf, sgG, scG, wc1, bc1, bK0, WQs, WKb, biasK);
    // 4. WQfull = WQs @ wg1 (MFMA) + biasQF
    k_wqfull<<<dim3(3, B), blk, 0, stream>>>(WQs, wg1bT, bQ0L, bg1, WQF, biasQF);
    // 5. merged projections (Fq now direct from X0T)
    k_proj<<<dim3(64, 3, B), blk, 0, stream>>>(
        X0T, BGcT, WQF, biasQF, WKb, biasK, whb, h_b, FqT, GkT, hvN);
    // 6. attention
    k_attn<<<256, 512, 0, stream>>>(FqT, GkT, hvN, mbuf, sbuf);
    // 7. fused mvn + transfer + cbam pools
    k_transfer_f<<<B * 64, blk, 0, stream>>>(mbuf, sbuf, FG, BG, BST, xb, pav, pmx);
    // 8/9. CBAM spatial
    k_sp_pool<<<dim3(HW / 256, B), blk, 0, stream>>>(xb, pav, pmx, mlp_w1, mlp_b1, mlp_w2, mlp_b2, spm, spx);
    k_spf<<<dim3(HW / 256, B), blk, 0, stream>>>(spm, spx, sp_w, sp_b, xb, pav, pmx, mlp_w1, mlp_b1, mlp_w2, mlp_b2, out);
}

// Round 20
// 164.420 us; speedup vs baseline: 1.0362x; 1.0362x over previous
//
#include <hip/hip_runtime.h>
#include <hip/hip_bf16.h>
#include <math.h>

#define HW 4096

typedef __attribute__((ext_vector_type(8))) short bf16x8;
typedef __attribute__((ext_vector_type(4))) float f32x4;

static __device__ __forceinline__ unsigned short f2bf(float x) {
    unsigned u = __float_as_uint(x);
    u += 0x7fffu + ((u >> 16) & 1u);     // RNE
    return (unsigned short)(u >> 16);
}
static __device__ __forceinline__ float bf2f(unsigned short h) {
    return __uint_as_float((unsigned)h << 16);
}
static __device__ __forceinline__ float g4(const float4& v, int k) {
    return k == 0 ? v.x : k == 1 ? v.y : k == 2 ? v.z : v.w;
}

// ---------------- transpose+bf16: z=0 group(192)->X0T, z=1 BGc(64)->BGcT
__global__ __launch_bounds__(256) void k_transpose2(
    const float* __restrict__ group, const float* __restrict__ BGc, int bstride,
    unsigned short* __restrict__ X0T, unsigned short* __restrict__ BGcT)
{
    extern __shared__ float lds[];          // [C][65]
    const int b = blockIdx.y, p0 = blockIdx.x << 6, t = threadIdx.x;
    const int z = blockIdx.z;
    const int C = z ? 64 : 192;
    const float* xb = (z ? BGc : group) + (size_t)b * bstride;
    unsigned short* outT = z ? BGcT : X0T;
    for (int idx = t; idx < (C << 6); idx += 256) {
        int c = idx >> 6, p = idx & 63;
        lds[c * 65 + p] = xb[(size_t)c * HW + p0 + p];
    }
    __syncthreads();
    unsigned short* ob = outT + ((size_t)b * HW + p0) * C;
    for (int idx = t; idx < (C << 6); idx += 256) {
        int p = idx / C, c = idx - p * C;
        ob[idx] = f2bf(lds[c * 65 + p]);
    }
}

// ---------------- per-(b,ci) mean over pixels of `group` (192 channels)
__global__ __launch_bounds__(256) void k_xmean(
    const float* __restrict__ g, int bstride, float* __restrict__ xmean)
{
    int bc = blockIdx.x;                 // B*192
    int b = bc / 192, ci = bc - b * 192;
    const float* p = g + (size_t)b * bstride + (size_t)ci * HW;
    int t = threadIdx.x;
    float s = 0.f;
    #pragma unroll 4
    for (int i = t; i < HW; i += 256) s += p[i];
    for (int o = 32; o > 0; o >>= 1) s += __shfl_down(s, o, 64);
    __shared__ float red[4];
    if ((t & 63) == 0) red[t >> 6] = s;
    __syncthreads();
    if (t == 0) xmean[bc] = (red[0] + red[1] + red[2] + red[3]) * (1.0f / HW);
}

// 4x4 register-tiled 64x64x64 f32 GEMM from padded LDS (A[64][68], B[64][68] as B[k][c])
static __device__ __forceinline__ void gemm64_tile(
    const float* A, const float* B, int t, float acc[4][4])
{
    const int tr = t >> 4, tc = t & 15;
    #pragma unroll
    for (int i = 0; i < 4; ++i)
        #pragma unroll
        for (int j = 0; j < 4; ++j) acc[i][j] = 0.f;
    for (int k4 = 0; k4 < 64; k4 += 4) {
        float4 a[4], bb[4];
        #pragma unroll
        for (int i = 0; i < 4; ++i) a[i]  = *(const float4*)&A[(4 * tr + i) * 68 + k4];
        #pragma unroll
        for (int kk = 0; kk < 4; ++kk) bb[kk] = *(const float4*)&B[(k4 + kk) * 68 + 4 * tc];
        #pragma unroll
        for (int i = 0; i < 4; ++i)
            #pragma unroll
            for (int kk = 0; kk < 4; ++kk)
                #pragma unroll
                for (int j = 0; j < 4; ++j)
                    acc[i][j] = fmaf(g4(a[i], kk), g4(bb[kk], j), acc[i][j]);
    }
}

// ---------------- prep: bid<4 = scales(b); bid>=4 = weight-chain(x).
__global__ __launch_bounds__(256) void k_prep(
    const float* __restrict__ xmean,
    const float* __restrict__ wg1, const float* __restrict__ bg1,
    const float* __restrict__ cag_w1, const float* __restrict__ cag_b1,
    const float* __restrict__ cag_w2, const float* __restrict__ cag_b2,
    const float* __restrict__ wc1, const float* __restrict__ bc1,
    const float* __restrict__ cac_w1, const float* __restrict__ cac_b1,
    const float* __restrict__ cac_w2, const float* __restrict__ cac_b2,
    const float* __restrict__ wg2, const float* __restrict__ bg2,
    const float* __restrict__ wg3, const float* __restrict__ bg3,
    const float* __restrict__ wc2, const float* __restrict__ bc2,
    const float* __restrict__ wf, const float* __restrict__ fb,
    const float* __restrict__ wgw, const float* __restrict__ gbv,
    const float* __restrict__ wh,
    float* __restrict__ W3L, float* __restrict__ Uf,
    float* __restrict__ bQ0L, float* __restrict__ bK0,
    float* __restrict__ sgG, float* __restrict__ scG,
    unsigned short* __restrict__ whb, unsigned short* __restrict__ wg1b)
{
    const float LOG2E = 1.4426950408889634f;
    __shared__ float sA[64 * 68], sB[64 * 68], sC[64 * 68];
    __shared__ float xm[192], pg[192], pc[64], zz[16];
    const int bid = blockIdx.x, t = threadIdx.x;

    if (bid >= 4) {
        const int x = bid - 4;
        #pragma unroll
        for (int j = 0; j < 16; ++j) {
            int idx = t + j * 256, r = idx >> 6, c = idx & 63;
            sA[r * 68 + c] = wf[idx];
            sB[r * 68 + c] = wg3[idx];
        }
        __syncthreads();
        float acc[4][4];
        gemm64_tile(sA, sB, t, acc);                   // V = wf@wg3
        {
            const int tr = t >> 4, tc = t & 15;
            #pragma unroll
            for (int i = 0; i < 4; ++i)
                #pragma unroll
                for (int j = 0; j < 4; ++j)
                    sC[(4 * tr + i) * 68 + 4 * tc + j] = acc[i][j];
        }
        __syncthreads();
        if (x == 0 && t < 64) {                        // bQ0L
            float a = fb[t];
            #pragma unroll 16
            for (int m = 0; m < 64; ++m) {
                a = fmaf(sC[t * 68 + m], bg2[m], a);
                a = fmaf(sA[t * 68 + m], bg3[m], a);
            }
            bQ0L[t] = a * LOG2E;
        }
        __syncthreads();
        for (int idx = t; idx < 3072; idx += 256) {    // sA[c][m] = wg2[m][x*48+c]
            int c = idx >> 6, m = idx & 63;
            sA[c * 68 + m] = wg2[m * 192 + x * 48 + c];
        }
        __syncthreads();
        {
            const int tr = t >> 4, tc = t & 15;
            float a2[4][3];
            #pragma unroll
            for (int i = 0; i < 4; ++i)
                #pragma unroll
                for (int j = 0; j < 3; ++j) a2[i][j] = 0.f;
            for (int k4 = 0; k4 < 64; k4 += 4) {
                float4 a[4], bb[3];
                #pragma unroll
                for (int i = 0; i < 4; ++i) a[i] = *(const float4*)&sC[(4 * tr + i) * 68 + k4];
                #pragma unroll
                for (int j = 0; j < 3; ++j) bb[j] = *(const float4*)&sA[(3 * tc + j) * 68 + k4];
                #pragma unroll
                for (int i = 0; i < 4; ++i)
                    #pragma unroll
                    for (int j = 0; j < 3; ++j)
                        #pragma unroll
                        for (int kk = 0; kk < 4; ++kk)
                            a2[i][j] = fmaf(g4(a[i], kk), g4(bb[j], kk), a2[i][j]);
            }
            #pragma unroll
            for (int i = 0; i < 4; ++i)
                #pragma unroll
                for (int j = 0; j < 3; ++j)
                    W3L[(4 * tr + i) * 192 + x * 48 + 3 * tc + j] = a2[i][j] * LOG2E;
        }
        if (x == 1) {                                   // U = wg@wc2, bK0
            __syncthreads();
            #pragma unroll
            for (int j = 0; j < 16; ++j) {
                int idx = t + j * 256, r = idx >> 6, c = idx & 63;
                sA[r * 68 + c] = wgw[idx];
                sB[r * 68 + c] = wc2[idx];
            }
            __syncthreads();
            float au[4][4];
            gemm64_tile(sA, sB, t, au);
            {
                const int tr = t >> 4, tc = t & 15;
                #pragma unroll
                for (int i = 0; i < 4; ++i)
                    #pragma unroll
                    for (int j = 0; j < 4; ++j)
                        Uf[(4 * tr + i) * 64 + 4 * tc + j] = au[i][j];
            }
            if (t < 64) {
                float a = gbv[t];
                #pragma unroll 16
                for (int m = 0; m < 64; ++m) a = fmaf(sA[t * 68 + m], bc2[m], a);
                bK0[t] = a;
            }
        }
        for (int idx = t; idx < 9216; idx += 256) {
            int g = x * 9216 + idx;
            wg1b[g] = f2bf(wg1[g]);
        }
        return;
    }

    // ---- scales role: b = bid
    const int b = bid, w = t >> 6, lane = t & 63;
    if (t < 192) xm[t] = xmean[b * 192 + t];
    __syncthreads();
    for (int r = w; r < 192; r += 4) {
        float part = 0.f;
        #pragma unroll
        for (int j = 0; j < 3; ++j)
            part = fmaf(wg1[r * 192 + lane + 64 * j], xm[lane + 64 * j], part);
        #pragma unroll
        for (int o = 32; o > 0; o >>= 1) part += __shfl_down(part, o, 64);
        if (lane == 0) pg[r] = part + bg1[r];
    }
    for (int r = w; r < 64; r += 4) {
        float part = wc1[r * 64 + lane] * xm[64 + lane];
        #pragma unroll
        for (int o = 32; o > 0; o >>= 1) part += __shfl_down(part, o, 64);
        if (lane == 0) pc[r] = part + bc1[r];
    }
    __syncthreads();
    if (t < 12) {
        float a = cag_b1[t];
        #pragma unroll 16
        for (int i = 0; i < 192; ++i) a = fmaf(cag_w1[t * 192 + i], pg[i], a);
        zz[t] = fmaxf(a, 0.f);
    }
    if (t >= 64 && t < 68) {
        int r = t - 64;
        float a = cac_b1[r];
        #pragma unroll 16
        for (int i = 0; i < 64; ++i) a = fmaf(cac_w1[r * 64 + i], pc[i], a);
        zz[12 + r] = fmaxf(a, 0.f);
    }
    __syncthreads();
    if (t < 192) {
        float a = cag_b2[t];
        #pragma unroll
        for (int j = 0; j < 12; ++j) a = fmaf(cag_w2[t * 12 + j], zz[j], a);
        sgG[b * 192 + t] = 1.f / (1.f + __expf(-a));
    } else {
        int c = t - 192;
        float a = cac_b2[c];
        #pragma unroll
        for (int j = 0; j < 4; ++j) a = fmaf(cac_w2[c * 4 + j], zz[12 + j], a);
        scG[b * 64 + c] = 1.f / (1.f + __expf(-a));
    }
    if (b == 0) {
        #pragma unroll
        for (int j = 0; j < 16; ++j) whb[t + j * 256] = f2bf(wh[t + j * 256]);
    }
}

// ---------------- per-batch finalize: bid<192 -> WQs scale; 192..195 -> WK GEMM + biasK
__global__ __launch_bounds__(256) void k_wscale(
    const float* __restrict__ W3L, const float* __restrict__ Uf,
    const float* __restrict__ sgG, const float* __restrict__ scG,
    const float* __restrict__ wc1, const float* __restrict__ bc1,
    const float* __restrict__ bK0,
    unsigned short* __restrict__ WQs, unsigned short* __restrict__ WKb,
    float* __restrict__ biasK)
{
    const int bid = blockIdx.x, t = threadIdx.x;
    if (bid < 192) {
        int i = bid * 256 + t;
        int b = i / 12288, rem = i - b * 12288;
        int c = rem % 192;
        WQs[i] = f2bf(W3L[rem] * sgG[b * 192 + c]);
        return;
    }
    __shared__ float Usc[64 * 68], sW[64 * 68], u2[64];
    const int b = bid - 192;
    #pragma unroll
    for (int j = 0; j < 16; ++j) {
        int idx = t + j * 256, r = idx >> 6, c = idx & 63;
        Usc[r * 68 + c] = Uf[idx] * scG[b * 64 + c];
        sW[r * 68 + c]  = wc1[idx];
    }
    if (t < 64) u2[t] = scG[b * 64 + t] * bc1[t];
    __syncthreads();
    float acc[4][4];
    gemm64_tile(Usc, sW, t, acc);
    const int tr = t >> 4, tc = t & 15;
    #pragma unroll
    for (int i = 0; i < 4; ++i)
        #pragma unroll
        for (int j = 0; j < 4; ++j)
            WKb[(size_t)b * 4096 + (4 * tr + i) * 64 + 4 * tc + j] = f2bf(acc[i][j]);
    if (t < 64) {
        float a = bK0[t];
        #pragma unroll 16
        for (int m = 0; m < 64; ++m) a = fmaf(Uf[t * 64 + m], u2[m], a);
        biasK[b * 64 + t] = a;
    }
}

// ---------------- MFMA conv: g1T = bf16(wg1 @ X0 + bg1)
__global__ __launch_bounds__(256) void k_gconv(
    const unsigned short* __restrict__ X0T, const unsigned short* __restrict__ wg1b,
    const float* __restrict__ bg1, unsigned short* __restrict__ g1T)
{
    const int t = threadIdx.x;
    const int w = t >> 6, lane = t & 63;
    const int gid = lane >> 4, cid = lane & 15;
    const int b = blockIdx.z;
    const int p0 = blockIdx.x << 6;
    const int co16 = ((blockIdx.y << 2) + w) << 4;
    const unsigned short* xrow = X0T + (size_t)b * HW * 192;
    const unsigned short* wr = wg1b + (size_t)co16 * 192;
    f32x4 acc[4];
    #pragma unroll
    for (int n = 0; n < 4; ++n)
        #pragma unroll
        for (int r = 0; r < 4; ++r)
            acc[n][r] = bg1[co16 + 4 * gid + r];
    for (int kc = 0; kc < 192; kc += 32) {
        bf16x8 a = *(const bf16x8*)(wr + (size_t)cid * 192 + kc + 8 * gid);
        #pragma unroll
        for (int n = 0; n < 4; ++n) {
            bf16x8 bfr = *(const bf16x8*)(xrow + (size_t)(p0 + 16 * n + cid) * 192 + kc + 8 * gid);
            acc[n] = __builtin_amdgcn_mfma_f32_16x16x32_bf16(a, bfr, acc[n], 0, 0, 0);
        }
    }
    #pragma unroll
    for (int n = 0; n < 4; ++n)
        #pragma unroll
        for (int r = 0; r < 4; ++r)
            g1T[((size_t)b * HW + p0 + 16 * n + cid) * 192 + co16 + 4 * gid + r] = f2bf(acc[n][r]);
}

// ---------------- merged MFMA projections: y=0 Fq (g1T,K=192), y=1 Gk (X0T@64,K=64), y=2 Hv
__global__ __launch_bounds__(256) void k_proj(
    const unsigned short* __restrict__ g1T, const unsigned short* __restrict__ X0T,
    const unsigned short* __restrict__ BGcT,
    const unsigned short* __restrict__ WQs, const float* __restrict__ bQ0L,
    const unsigned short* __restrict__ WKb, const float* __restrict__ biasK,
    const unsigned short* __restrict__ whb, const float* __restrict__ h_b,
    unsigned short* __restrict__ FqT, unsigned short* __restrict__ GkT,
    unsigned short* __restrict__ hvN)
{
    const int t = threadIdx.x;
    const int w = t >> 6, lane = t & 63;
    const int gid = lane >> 4, cid = lane & 15;
    const int which = blockIdx.y;
    const int b = blockIdx.z;
    const int p0 = blockIdx.x << 6;
    const int co16 = w << 4;
    int Cin, kOff, ldx;
    const unsigned short *XT, *W;
    const float* bp;
    if (which == 0)      { XT = g1T;  ldx = 192; kOff = 0;  Cin = 192; W = WQs + (size_t)b * 12288; bp = bQ0L; }
    else if (which == 1) { XT = X0T;  ldx = 192; kOff = 64; Cin = 64;  W = WKb + (size_t)b * 4096;  bp = biasK + b * 64; }
    else                 { XT = BGcT; ldx = 64;  kOff = 0;  Cin = 64;  W = whb;                      bp = h_b; }
    const unsigned short* xrow = XT + (size_t)b * HW * ldx + kOff;
    const unsigned short* wr = W + (size_t)co16 * Cin;
    f32x4 acc[4];
    #pragma unroll
    for (int n = 0; n < 4; ++n)
        #pragma unroll
        for (int r = 0; r < 4; ++r)
            acc[n][r] = bp[co16 + 4 * gid + r];
    for (int kc = 0; kc < Cin; kc += 32) {
        bf16x8 a = *(const bf16x8*)(wr + (size_t)cid * Cin + kc + 8 * gid);
        #pragma unroll
        for (int n = 0; n < 4; ++n) {
            bf16x8 bfr = *(const bf16x8*)(xrow + (size_t)(p0 + 16 * n + cid) * ldx + kc + 8 * gid);
            acc[n] = __builtin_amdgcn_mfma_f32_16x16x32_bf16(a, bfr, acc[n], 0, 0, 0);
        }
    }
    #pragma unroll
    for (int n = 0; n < 4; ++n)
        #pragma unroll
        for (int r = 0; r < 4; ++r) {
            float v = acc[n][r];
            int co = co16 + 4 * gid + r;
            int p  = p0 + 16 * n + cid;
            if (which == 0)      FqT[((size_t)b * HW + p) * 64 + co] = f2bf(v);
            else if (which == 1) GkT[((size_t)b * HW + p) * 64 + co] = f2bf(v);
            else                 hvN[((size_t)b * 64 + co) * HW + p] = f2bf(v);
        }
}

// ---------------- MFMA attention (proven round-8/15 config, exp2, in-reg Hv^2).
__global__ __launch_bounds__(512, 2) void k_attn(
    const unsigned short* __restrict__ FqT, const unsigned short* __restrict__ GkT,
    const unsigned short* __restrict__ HvN,
    float* __restrict__ mb, float* __restrict__ sbuf)
{
    __shared__ __align__(16) char smem[65536];
    const int t = threadIdx.x;
    const int bid = blockIdx.x;
    const int b = (bid & 7) >> 1;
    const int qbase = (((bid >> 3) << 1) | (bid & 1)) << 6;
    const int w = t >> 6, lane = t & 63;
    const int gid = lane >> 4, cid = lane & 15;
    const size_t CQ = (size_t)HW * 64;
    const unsigned short* fqt = FqT + (size_t)b * CQ;
    const unsigned short* gkt = GkT + (size_t)b * CQ;
    const unsigned short* hv  = HvN + (size_t)b * CQ;
    unsigned short* Pw = (unsigned short*)smem + w * 4096;

    bf16x8 fqa[4][2];
    #pragma unroll
    for (int qt = 0; qt < 4; ++qt) {
        const unsigned short* fr = fqt + (size_t)(qbase + 16 * qt + cid) * 64 + 8 * gid;
        fqa[qt][0] = *(const bf16x8*)fr;
        fqa[qt][1] = *(const bf16x8*)(fr + 32);
    }
    bf16x8 ones;
    #pragma unroll
    for (int j = 0; j < 8; ++j) ones[j] = (short)0x3F80;

    const f32x4 fz = {0.f, 0.f, 0.f, 0.f};
    f32x4 am[4][4], a2[4][4], lac[4];
    #pragma unroll
    for (int qt = 0; qt < 4; ++qt) {
        lac[qt] = fz;
        #pragma unroll
        for (int n = 0; n < 4; ++n) { am[qt][n] = fz; a2[qt][n] = fz; }
    }

    const int k00 = w << 9;
    for (int it = 0; it < 8; ++it) {
        const int k0 = k00 + (it << 6);
        #pragma unroll
        for (int n = 0; n < 4; ++n) {
            const unsigned short* gr = gkt + (size_t)(k0 + 16 * n + cid) * 64 + 8 * gid;
            bf16x8 b0 = *(const bf16x8*)gr;
            bf16x8 b1 = *(const bf16x8*)(gr + 32);
            const int k = 16 * n + cid;
            #pragma unroll
            for (int qt = 0; qt < 4; ++qt) {
                f32x4 s = __builtin_amdgcn_mfma_f32_16x16x32_bf16(fqa[qt][0], b0, fz, 0, 0, 0);
                s = __builtin_amdgcn_mfma_f32_16x16x32_bf16(fqa[qt][1], b1, s, 0, 0, 0);
                #pragma unroll
                for (int r = 0; r < 4; ++r) {
                    int q = 4 * gid + r;
                    Pw[qt * 1024 + q * 64 + (((k >> 3) ^ (q & 7)) << 3) + (k & 7)] =
                        f2bf(__builtin_amdgcn_exp2f(s[r]));
                }
            }
        }
        bf16x8 pa[4][2];
        #pragma unroll
        for (int qt = 0; qt < 4; ++qt)
            #pragma unroll
            for (int kh = 0; kh < 2; ++kh)
                pa[qt][kh] = *(const bf16x8*)(Pw + qt * 1024 + cid * 64 +
                                              (((4 * kh + gid) ^ (cid & 7)) << 3));
        #pragma unroll
        for (int qt = 0; qt < 4; ++qt) {
            lac[qt] = __builtin_amdgcn_mfma_f32_16x16x32_bf16(pa[qt][0], ones, lac[qt], 0, 0, 0);
            lac[qt] = __builtin_amdgcn_mfma_f32_16x16x32_bf16(pa[qt][1], ones, lac[qt], 0, 0, 0);
        }
        #pragma unroll
        for (int n = 0; n < 4; ++n) {
            const unsigned short* hr = hv + (size_t)(16 * n + cid) * HW + k0;
            #pragma unroll
            for (int kh = 0; kh < 2; ++kh) {
                bf16x8 hb = *(const bf16x8*)(hr + 32 * kh + 8 * gid);
                bf16x8 h2;
                #pragma unroll
                for (int j = 0; j < 8; ++j) {
                    float v = bf2f((unsigned short)hb[j]);
                    h2[j] = (short)f2bf(v * v);
                }
                #pragma unroll
                for (int qt = 0; qt < 4; ++qt) {
                    am[qt][n] = __builtin_amdgcn_mfma_f32_16x16x32_bf16(pa[qt][kh], hb, am[qt][n], 0, 0, 0);
                    a2[qt][n] = __builtin_amdgcn_mfma_f32_16x16x32_bf16(pa[qt][kh], h2, a2[qt][n], 0, 0, 0);
                }
            }
        }
    }

    __syncthreads();
    float* lb = (float*)smem;
    #pragma unroll
    for (int qt = 0; qt < 4; ++qt)
        *(f32x4*)(lb + ((size_t)(w * 4 + qt) * 64 + lane) * 4) = lac[qt];
    __syncthreads();
    float* Lm = (float*)(smem + 32768);
    if (t < 256) {
        int qt = t >> 6, ls = t & 63;
        f32x4 s = fz;
        #pragma unroll
        for (int ww = 0; ww < 8; ++ww)
            s += *(const f32x4*)(lb + ((size_t)(ww * 4 + qt) * 64 + ls) * 4);
        *(f32x4*)(Lm + ((size_t)qt * 64 + ls) * 4) = s;
    }
    __syncthreads();
    float* ab = (float*)smem;
    f32x4 meanv = fz;
    for (int qt = 0; qt < 4; ++qt) {
        #pragma unroll
        for (int n = 0; n < 4; ++n)
            *(f32x4*)(ab + ((size_t)(w * 4 + n) * 64 + lane) * 4) = am[qt][n];
        __syncthreads();
        if (t < 256) {
            int n = t >> 6, ls = t & 63;
            f32x4 s = fz;
            #pragma unroll
            for (int ww = 0; ww < 8; ++ww)
                s += *(const f32x4*)(ab + ((size_t)(ww * 4 + n) * 64 + ls) * 4);
            f32x4 lv = *(const f32x4*)(Lm + ((size_t)qt * 64 + ls) * 4);
            #pragma unroll
            for (int r = 0; r < 4; ++r) meanv[r] = s[r] / lv[r];
            int q0s = qbase + 16 * qt + 4 * (ls >> 4);
            int c   = 16 * n + (ls & 15);
            *(f32x4*)(mb + (size_t)b * CQ + (size_t)c * HW + q0s) = meanv;
        }
        __syncthreads();
        #pragma unroll
        for (int n = 0; n < 4; ++n)
            *(f32x4*)(ab + ((size_t)(w * 4 + n) * 64 + lane) * 4) = a2[qt][n];
        __syncthreads();
        if (t < 256) {
            int n = t >> 6, ls = t & 63;
            f32x4 s = fz;
            #pragma unroll
            for (int ww = 0; ww < 8; ++ww)
                s += *(const f32x4*)(ab + ((size_t)(ww * 4 + n) * 64 + ls) * 4);
            f32x4 lv = *(const f32x4*)(Lm + ((size_t)qt * 64 + ls) * 4);
            f32x4 sv;
            #pragma unroll
            for (int r = 0; r < 4; ++r) {
                float sec = s[r] / lv[r];
                sv[r] = sqrtf(fmaxf(sec - meanv[r] * meanv[r], 0.f));
            }
            int q0s = qbase + 16 * qt + 4 * (ls >> 4);
            int c   = 16 * n + (ls & 15);
            *(f32x4*)(sbuf + (size_t)b * CQ + (size_t)c * HW + q0s) = sv;
        }
        __syncthreads();
    }
}

// ---------------- fused: mvn stats + transfer + cbam channel pools
__global__ __launch_bounds__(256) void k_transfer_f(
    const float* __restrict__ mb, const float* __restrict__ sb,
    const float* __restrict__ FG, const float* __restrict__ BG, int bstride,
    float* __restrict__ xb, float* __restrict__ pavg, float* __restrict__ pmaxb)
{
    __shared__ float fgl[4096];
    __shared__ float r1[4], r2[4];
    const int bc = blockIdx.x, t = threadIdx.x;
    const int b = bc >> 6, c = bc & 63;
    const size_t row = (size_t)bc * HW;
    const float* fg = FG + (size_t)b * bstride + (size_t)(64 + c) * HW;
    const float* bg = BG + (size_t)b * bstride + (size_t)(64 + c) * HW;
    float s = 0.f, s2 = 0.f;
    #pragma unroll
    for (int j = 0; j < 16; ++j) {
        int i = t + j * 256;
        float v = fg[i];
        fgl[i] = v;
        s += v; s2 += v * v;
    }
    #pragma unroll
    for (int o = 32; o > 0; o >>= 1) { s += __shfl_down(s, o, 64); s2 += __shfl_down(s2, o, 64); }
    if ((t & 63) == 0) { r1[t >> 6] = s; r2[t >> 6] = s2; }
    __syncthreads();
    float m  = (r1[0] + r1[1] + r1[2] + r1[3]) * (1.0f / HW);
    float e2 = (r2[0] + r2[1] + r2[2] + r2[3]) * (1.0f / HW);
    float rs = rsqrtf(fmaxf(e2 - m * m, 0.f) + 1e-5f);
    float psum = 0.f, pmax = -1e30f;
    #pragma unroll
    for (int j = 0; j < 16; ++j) {
        int q = t + j * 256;
        float xv = sb[row + q] * (fgl[q] - m) * rs + mb[row + q] + bg[q];
        xb[row + q] = xv;
        psum += xv; pmax = fmaxf(pmax, xv);
    }
    __syncthreads();
    #pragma unroll
    for (int o = 32; o > 0; o >>= 1) {
        psum += __shfl_down(psum, o, 64);
        pmax = fmaxf(pmax, __shfl_down(pmax, o, 64));
    }
    if ((t & 63) == 0) { r1[t >> 6] = psum; r2[t >> 6] = pmax; }
    __syncthreads();
    if (t == 0) {
        pavg[bc]  = (r1[0] + r1[1] + r1[2] + r1[3]) * (1.0f / HW);
        pmaxb[bc] = fmaxf(fmaxf(r2[0], r2[1]), fmaxf(r2[2], r2[3]));
    }
}

// ---------------- CBAM channel-scale (recomputed per block)
static __device__ __forceinline__ void cbam_scale(
    const float* __restrict__ pav, const float* __restrict__ pmx,
    const float* __restrict__ w1, const float* __restrict__ b1,
    const float* __restrict__ w2, const float* __restrict__ b2,
    int b, int t, float* scb)
{
    __shared__ float za[4], zm[4];
    if (t < 4) {
        float aa = b1[t], am = b1[t];
        #pragma unroll 16
        for (int i = 0; i < 64; ++i) {
            aa = fmaf(w1[t * 64 + i], pav[b * 64 + i], aa);
            am = fmaf(w1[t * 64 + i], pmx[b * 64 + i], am);
        }
        za[t] = fmaxf(aa, 0.f);
        zm[t] = fmaxf(am, 0.f);
    }
    __syncthreads();
    if (t < 64) {
        float a = 2.f * b2[t];
        #pragma unroll
        for (int j = 0; j < 4; ++j) a = fmaf(w2[t * 4 + j], za[j] + zm[j], a);
        scb[t] = 1.f / (1.f + __expf(-a));
    }
    __syncthreads();
}

// ---------------- spatial pool of (xb*s) with inlined cbam MLP
__global__ __launch_bounds__(256) void k_sp_pool(
    const float* __restrict__ xb,
    const float* __restrict__ pav, const float* __restrict__ pmx,
    const float* __restrict__ w1, const float* __restrict__ b1,
    const float* __restrict__ w2, const float* __restrict__ b2,
    float* __restrict__ spm, float* __restrict__ spx)
{
    __shared__ float scb[64];
    const int b = blockIdx.y, t = threadIdx.x;
    cbam_scale(pav, pmx, w1, b1, w2, b2, b, t, scb);
    const int p = blockIdx.x * 256 + t;
    const float* xp = xb + (size_t)b * 262144 + p;
    float sum = 0.f, mx = -1e30f;
    #pragma unroll 8
    for (int c = 0; c < 64; ++c) {
        float v = xp[(size_t)c * HW] * scb[c];
        sum += v;
        mx = fmaxf(mx, v);
    }
    spm[b * HW + p] = sum * (1.0f / 64.0f);
    spx[b * HW + p] = mx;
}

// ---------------- fused 7x7 spatial conv + sigmoid + final output
__global__ __launch_bounds__(256) void k_spf(
    const float* __restrict__ spm, const float* __restrict__ spx,
    const float* __restrict__ w, const float* __restrict__ bias,
    const float* __restrict__ xb,
    const float* __restrict__ pav, const float* __restrict__ pmx,
    const float* __restrict__ w1, const float* __restrict__ b1,
    const float* __restrict__ w2, const float* __restrict__ b2,
    float* __restrict__ out)
{
    __shared__ float scb[64];
    const int b = blockIdx.y, t = threadIdx.x;
    cbam_scale(pav, pmx, w1, b1, w2, b2, b, t, scb);
    const int p = blockIdx.x * 256 + t;
    const int y = p >> 6, x = p & 63;
    float acc = bias[0];
    for (int dy = 0; dy < 7; ++dy) {
        int yy = y + dy - 3;
        if (yy < 0 || yy >= 64) continue;
        for (int dx = 0; dx < 7; ++dx) {
            int xx = x + dx - 3;
            if (xx < 0 || xx >= 64) continue;
            int q = b * HW + yy * 64 + xx;
            acc = fmaf(spm[q], w[dy * 7 + dx],      acc);
            acc = fmaf(spx[q], w[49 + dy * 7 + dx], acc);
        }
    }
    float sgm = 1.f / (1.f + __expf(-acc));
    const float* xp = xb + (size_t)b * 262144 + p;
    float* op = out + (size_t)b * 262144 + p;
    #pragma unroll 8
    for (int c = 0; c < 64; ++c)
        op[(size_t)c * HW] = xp[(size_t)c * HW] * scb[c] * sgm;
}

extern "C" void kernel_launch(void* const* d_in, const int* in_sizes, int n_in,
                              void* d_out, int out_size, void* d_ws, size_t ws_size,
                              hipStream_t stream)
{
    const float* group  = (const float*)d_in[0];
    const float* FG     = (const float*)d_in[1];
    const float* BG     = (const float*)d_in[2];
    const float* wg1    = (const float*)d_in[3];
    const float* bg1    = (const float*)d_in[4];
    const float* cag_w1 = (const float*)d_in[5];
    const float* cag_b1 = (const float*)d_in[6];
    const float* cag_w2 = (const float*)d_in[7];
    const float* cag_b2 = (const float*)d_in[8];
    const float* wg2    = (const float*)d_in[9];
    const float* bg2    = (const float*)d_in[10];
    const float* wg3    = (const float*)d_in[11];
    const float* bg3    = (const float*)d_in[12];
    const float* wc1    = (const float*)d_in[13];
    const float* bc1    = (const float*)d_in[14];
    const float* cac_w1 = (const float*)d_in[15];
    const float* cac_b1 = (const float*)d_in[16];
    const float* cac_w2 = (const float*)d_in[17];
    const float* cac_b2 = (const float*)d_in[18];
    const float* wc2    = (const float*)d_in[19];
    const float* bc2    = (const float*)d_in[20];
    const float* f_w    = (const float*)d_in[21];
    const float* f_b    = (const float*)d_in[22];
    const float* g_w    = (const float*)d_in[23];
    const float* g_b    = (const float*)d_in[24];
    const float* h_w    = (const float*)d_in[25];
    const float* h_b    = (const float*)d_in[26];
    const float* mlp_w1 = (const float*)d_in[27];
    const float* mlp_b1 = (const float*)d_in[28];
    const float* mlp_w2 = (const float*)d_in[29];
    const float* mlp_b2 = (const float*)d_in[30];
    const float* sp_w   = (const float*)d_in[31];
    const float* sp_b   = (const float*)d_in[32];
    float* out = (float*)d_out;

    const int B = 4;
    const size_t CHW = (size_t)64 * HW;
    const int BST = (int)(3 * CHW);

    float* ws = (float*)d_ws;
    const size_t M = 1048576;
    unsigned short* X0T  = (unsigned short*)ws;                 // [0,1.5M)f
    unsigned short* BGcT = (unsigned short*)(ws + 3 * M / 2);   // [1.5M,2M)
    unsigned short* g1T  = (unsigned short*)(ws + 2 * M);       // [2M,3.5M)
    unsigned short* FqT  = (unsigned short*)(ws + 7 * M / 2);   // [3.5M,4M)
    unsigned short* GkT  = (unsigned short*)(ws + 4 * M);       // [4M,4.5M)
    unsigned short* hvN  = (unsigned short*)(ws + 9 * M / 2);   // [4.5M,5M)
    float* mbuf = ws + 5 * M;       // [5M,6M)
    float* sbuf = ws + 6 * M;       // [6M,7M)
    float* xb   = ws;               // [0,1M) over X0T (dead after proj)
    float* smalls = ws + 7 * M;
    float* xmean = smalls;             // 768
    float* sgG   = smalls + 768;       // 768
    float* scG   = smalls + 1536;      // 256
    float* pav   = smalls + 1792;      // 256
    float* pmx   = smalls + 2048;      // 256
    float* biasK = smalls + 2304;      // 256
    float* bQ0L  = smalls + 2560;      // 64
    float* bK0   = smalls + 2624;      // 64
    float* Uf    = smalls + 2688;      // 4096
    float* W3L   = smalls + 6784;      // 12288
    float* spm   = smalls + 19072;     // 16384
    float* spx   = smalls + 35456;     // 16384
    unsigned short* wsh = (unsigned short*)(smalls + 51840);
    unsigned short* WQs  = wsh;              // 49152
    unsigned short* WKb  = wsh + 49152;      // 16384
    unsigned short* whb  = wsh + 65536;      // 4096
    unsigned short* wg1b = wsh + 69632;      // 36864

    dim3 blk(256);

    // 1. input transposes
    k_transpose2<<<dim3(64, B, 2), blk, 192 * 65 * 4, stream>>>(group, BG + CHW, BST, X0T, BGcT);
    // 2. channel means of group
    k_xmean<<<B * 192, blk, 0, stream>>>(group, BST, xmean);
    // 3. scales + weight chain
    k_prep<<<8, blk, 0, stream>>>(
        xmean, wg1, bg1, cag_w1, cag_b1, cag_w2, cag_b2,
        wc1, bc1, cac_w1, cac_b1, cac_w2, cac_b2,
        wg2, bg2, wg3, bg3, wc2, bc2,
        f_w, f_b, g_w, g_b, h_w,
        W3L, Uf, bQ0L, bK0, sgG, scG, whb, wg1b);
    // 4. per-batch WQ scale + WK GEMM + biasK
    k_wscale<<<196, blk, 0, stream>>>(W3L, Uf, sgG, scG, wc1, bc1, bK0, WQs, WKb, biasK);
    // 5. g1 conv (MFMA)
    k_gconv<<<dim3(64, 3, B), blk, 0, stream>>>(X0T, wg1b, bg1, g1T);
    // 6. merged projections
    k_proj<<<dim3(64, 3, B), blk, 0, stream>>>(
        g1T, X0T, BGcT, WQs, bQ0L, WKb, biasK, whb, h_b, FqT, GkT, hvN);
    // 7. attention
    k_attn<<<256, 512, 0, stream>>>(FqT, GkT, hvN, mbuf, sbuf);
    // 8. fused mvn + transfer + cbam pools
    k_transfer_f<<<B * 64, blk, 0, stream>>>(mbuf, sbuf, FG, BG, BST, xb, pav, pmx);
    // 9/10. CBAM spatial
    k_sp_pool<<<dim3(HW / 256, B), blk, 0, stream>>>(xb, pav, pmx, mlp_w1, mlp_b1, mlp_w2, mlp_b2, spm, spx);
    k_spf<<<dim3(HW / 256, B), blk, 0, stream>>>(spm, spx, sp_w, sp_b, xb, pav, pmx, mlp_w1, mlp_b1, mlp_w2, mlp_b2, out);
}